// Round 9
// baseline (450.601 us; speedup 1.0000x reference)
//
#include <hip/hip_runtime.h>

// GNN layer: messages = relu(NF @ Wm^T + bm); agg = (adj @ messages)/deg; GRU(agg, NF)
// N=8192, D=128. adj read 268 MB = the floor. bf16 MFMA 16x16x32.
// V8b (resubmit; R8 was an infra failure like R4): ONE barrier/iter K2, BK=64, both
// tiles double-buffered (42 KB LDS -> 3 blocks/CU, 24 waves/CU). B staged via
// global_load_lds (async DMA, linear dest) with XOR-swizzle applied BOTH sides:
// pre-swizzled global source + swizzled read (rule: both-sides-or-neither).
// A on the proven reg-convert path, 1 int4/thread/iter. Micro-fix vs V8: the A(c+1)
// prefetch now issues AFTER the barrier (V8 issued it before, so the barrier's
// vmcnt(0) drained it instantly -- zero coverage). K1/K3 unchanged (verified).

#define NN 8192
#define DIM 128
#define LSTR 136   // 128 + 8 bf16 pad (K1/K3 tiles)
#define ASTR 72    // 64 + 8 bf16 pad (K2 A tile row)
#define KSPLIT 8

typedef __bf16 bf16x8 __attribute__((ext_vector_type(8)));
typedef float f32x4 __attribute__((ext_vector_type(4)));

__device__ __forceinline__ unsigned short f2bf(float f) {
  union { float f; unsigned u; } v; v.f = f;
  unsigned r = v.u + 0x7FFF + ((v.u >> 16) & 1);  // RNE
  return (unsigned short)(r >> 16);
}
__device__ __forceinline__ ushort4 f2bf4(float4 f) {
  ushort4 u; u.x = f2bf(f.x); u.y = f2bf(f.y); u.z = f2bf(f.z); u.w = f2bf(f.w);
  return u;
}
__device__ __forceinline__ float sigmoidf_(float x) {
  return 1.0f / (1.0f + __expf(-x));
}
__device__ __forceinline__ float tanhf_(float x) {
  float e = __expf(-2.0f * fabsf(x));
  float r = (1.0f - e) / (1.0f + e);
  return x < 0.0f ? -r : r;
}
// async 16B/lane global->LDS (lds dest wave-uniform; HW adds lane*16)
__device__ __forceinline__ void gload16(const unsigned short* g, unsigned short* l) {
  __builtin_amdgcn_global_load_lds(
      (const __attribute__((address_space(1))) unsigned int*)g,
      (__attribute__((address_space(3))) unsigned int*)l, 16, 0, 0);
}

// ---------------- K1: msgT[o][m] = relu(NF @ Wm^T + bm) (bf16, transposed).
// Side jobs: nfB = bf16(nf), wihB/whhB = bf16 GRU weights (converted once).
__global__ __launch_bounds__(256) void k1_msg(
    const float* __restrict__ nf, const float* __restrict__ w_msg,
    const float* __restrict__ b_msg, unsigned short* __restrict__ msgT,
    unsigned short* __restrict__ nfB, const float* __restrict__ w_ih,
    const float* __restrict__ w_hh, unsigned short* __restrict__ wihB,
    unsigned short* __restrict__ whhB) {
  __shared__ unsigned short wm[128 * LSTR];   // wm[o][k] bf16
  __shared__ unsigned short nfl[32 * LSTR];   // nf tile [m][k] bf16
  const int t = threadIdx.x;
  const int m0 = blockIdx.x * 32;

  const int gtid = blockIdx.x * 256 + t;
  if (gtid < 12288) {
    ((ushort4*)wihB)[gtid] = f2bf4(((const float4*)w_ih)[gtid]);
  } else if (gtid < 24576) {
    ((ushort4*)whhB)[gtid - 12288] = f2bf4(((const float4*)w_hh)[gtid - 12288]);
  }
  for (int i = t; i < 4096; i += 256) {
    float4 v = ((const float4*)w_msg)[i];
    const int row = i >> 5, col = (i & 31) * 4;
    *(ushort4*)&wm[row * LSTR + col] = f2bf4(v);
  }
  for (int i = t; i < 1024; i += 256) {
    float4 v = ((const float4*)(nf + m0 * 128))[i];
    ushort4 u = f2bf4(v);
    const int row = i >> 5, col = (i & 31) * 4;
    *(ushort4*)&nfl[row * LSTR + col] = u;
    *(ushort4*)&nfB[(m0 + row) * 128 + col] = u;
  }
  __syncthreads();

  const int lane = t & 63, wave = t >> 6;
  const int quad = lane >> 4, l16 = lane & 15;
  const int rt = wave >> 1, ch = wave & 1;
  f32x4 acc[4];
  for (int j = 0; j < 4; ++j) acc[j] = (f32x4){0.f, 0.f, 0.f, 0.f};
  for (int kk = 0; kk < 4; ++kk) {
    bf16x8 a = *(const bf16x8*)&nfl[(rt * 16 + l16) * LSTR + kk * 32 + quad * 8];
    for (int j = 0; j < 4; ++j) {
      const int ct = ch * 4 + j;
      bf16x8 b = *(const bf16x8*)&wm[(ct * 16 + l16) * LSTR + kk * 32 + quad * 8];
      acc[j] = __builtin_amdgcn_mfma_f32_16x16x32_bf16(a, b, acc[j], 0, 0, 0);
    }
  }
  const int mb = m0 + rt * 16 + quad * 4;
  for (int j = 0; j < 4; ++j) {
    const int o = (ch * 4 + j) * 16 + l16;
    const float bias = b_msg[o];
    ushort4 u;
    u.x = f2bf(fmaxf(acc[j][0] + bias, 0.0f));
    u.y = f2bf(fmaxf(acc[j][1] + bias, 0.0f));
    u.z = f2bf(fmaxf(acc[j][2] + bias, 0.0f));
    u.w = f2bf(fmaxf(acc[j][3] + bias, 0.0f));
    *(ushort4*)&msgT[o * NN + mb] = u;
  }
}

// ---------------- K2: 2048 WGs x 512 thr. M-tile 32, BK=64, 16 iters, ONE barrier
// per iter. A: reg->convert->LDS dbuf (padded). B: global_load_lds into linear LDS
// dbuf, source pre-swizzled (chunk ^= row&7), read swizzled. aggP f32 partials.
__global__ __launch_bounds__(512) void k2_agg(
    const int* __restrict__ adj, const unsigned short* __restrict__ msgT,
    float* __restrict__ aggP, int* __restrict__ degP) {
  __shared__ unsigned short adjL[2][32 * ASTR];   // 2 x 4.6 KB bf16 (0/1)
  __shared__ unsigned short bufB[2][128 * 64];    // 2 x 16 KB bf16, linear (DMA dest)
  __shared__ int degS[32];
  const int t = threadIdx.x;
  const int mt = blockIdx.x & 255;  // 256 m-tiles of 32 rows
  const int ks = blockIdx.x >> 8;   // 8 k-chunks of 1024
  const int m0 = mt * 32;
  const int kbase = ks * 1024;
  if (t < 32) degS[t] = 0;

  const int lane = t & 63, wave = t >> 6;
  const int quad = lane >> 4, l16 = lane & 15;

  // A staging: thread t owns row ar = t>>4 (0..31), int4 segment as = t&15 (64 ints/row)
  const int ar = t >> 4, as = t & 15;
  const int* aB = adj + (size_t)(m0 + ar) * NN + kbase + as * 4;

  // B staging: 2 gload16/thread; instr j of wave w fills LDS bytes [(w*2+j)*1024,+1024)
  // lane covers row (w*2+j)*8 + (lane>>3), chunk-slot lane&7; source chunk = slot^(row&7)
  const int brow0 = (wave * 2 + 0) * 8 + (lane >> 3);
  const int brow1 = (wave * 2 + 1) * 8 + (lane >> 3);
  const int bchk = (lane & 7) ^ (lane >> 3);   // row&7 == lane>>3 for both rows
  const unsigned short* bG0 = msgT + (size_t)brow0 * NN + kbase + bchk * 8;
  const unsigned short* bG1 = msgT + (size_t)brow1 * NN + kbase + bchk * 8;

  // compute-side indices
  const int rt = wave >> 2;              // waves 0-3: rows 0-15; 4-7: rows 16-31
  const int ct0 = (wave & 3) * 2, ct1 = ct0 + 1;
  const int aOff = (rt * 16 + l16) * ASTR + quad * 8;
  // B read: row = ct*16+l16 (stride 64 ush), phys chunk = (kk*4+quad) ^ (l16&7)
  const int bx0 = (ct0 * 16 + l16) * 64;
  const int bx1 = (ct1 * 16 + l16) * 64;
  const int sw = (l16 & 7);

  f32x4 acc0 = {0.f, 0.f, 0.f, 0.f}, acc1 = {0.f, 0.f, 0.f, 0.f};
  int deg = 0;

  // prologue: A(0) regs + B(0) DMA
  int4 pa = *(const int4*)aB;
  gload16(bG0, &bufB[0][(wave * 2 + 0) * 512]);
  gload16(bG1, &bufB[0][(wave * 2 + 1) * 512]);

#pragma unroll
  for (int c = 0; c < 16; ++c) {
    // drain A(c): int 0/1 -> bf16 + degree
    ushort4 w;
    w.x = pa.x ? 0x3F80 : 0; w.y = pa.y ? 0x3F80 : 0;
    w.z = pa.z ? 0x3F80 : 0; w.w = pa.w ? 0x3F80 : 0;
    deg += pa.x + pa.y + pa.z + pa.w;
    *(ushort4*)&adjL[c & 1][ar * ASTR + as * 4] = w;
    __syncthreads();  // vmcnt(0): B(c) landed; adjL[c&1] visible; prev compute done
    // issue B(c+1) DMA + A(c+1) prefetch: both get the whole compute phase to land
    // (B(c+1)'s buffer readers finished before the barrier above)
    int4 na;
    if (c < 15) {
      const int kof = (c + 1) * 64;
      gload16(bG0 + kof, &bufB[(c + 1) & 1][(wave * 2 + 0) * 512]);
      gload16(bG1 + kof, &bufB[(c + 1) & 1][(wave * 2 + 1) * 512]);
      na = *(const int4*)(aB + (c + 1) * 64);
    }
    // compute from adjL[c&1], bufB[c&1]
#pragma unroll
    for (int kk = 0; kk < 2; ++kk) {
      const int pc = ((kk * 4 + quad) ^ sw) * 8;
      bf16x8 a  = *(const bf16x8*)&adjL[c & 1][aOff + kk * 32];
      bf16x8 b0 = *(const bf16x8*)&bufB[c & 1][bx0 + pc];
      bf16x8 b1 = *(const bf16x8*)&bufB[c & 1][bx1 + pc];
      acc0 = __builtin_amdgcn_mfma_f32_16x16x32_bf16(a, b0, acc0, 0, 0, 0);
      acc1 = __builtin_amdgcn_mfma_f32_16x16x32_bf16(a, b1, acc1, 0, 0, 0);
    }
    pa = na;
  }

  atomicAdd(&degS[ar], deg);
  __syncthreads();
  if (t < 32) degP[ks * NN + m0 + t] = degS[t];
  float* dst = aggP + (size_t)ks * NN * 128;
  for (int r = 0; r < 4; ++r) {
    const int rowL = rt * 16 + quad * 4 + r;
    const int m = m0 + rowL;
    dst[(size_t)m * 128 + ct0 * 16 + l16] = acc0[r];
    dst[(size_t)m * 128 + ct1 * 16 + l16] = acc1[r];
  }
}

// ---------------- K3: fused GRU, 512 thr / 32-row tiles (grid 256).
// agg = (sum_ks P_ks)/deg combined f32 at staging; B-frags direct from bf16
// weights (L2-resident), 1 barrier total.
__global__ __launch_bounds__(512) void k3_gru(
    const float* __restrict__ nf, const float* __restrict__ aggP,
    const int* __restrict__ degP, const unsigned short* __restrict__ wihB,
    const unsigned short* __restrict__ whhB, const float* __restrict__ b_ih,
    const float* __restrict__ b_hh, const unsigned short* __restrict__ nfB,
    float* __restrict__ out) {
  __shared__ unsigned short aggL[32 * LSTR];
  __shared__ unsigned short nfL[32 * LSTR];
  const int t = threadIdx.x;
  const int m0 = blockIdx.x * 32;
  {
    const int r_ = t >> 4, c8 = (t & 15) * 8;  // 512 thr cover 32 rows x 128 cols
    int dsum = 0;
#pragma unroll
    for (int ks = 0; ks < KSPLIT; ++ks) dsum += degP[ks * NN + m0 + r_];
    const float inv = 1.0f / fmaxf((float)dsum, 1.0f);
    float4 s0 = {0.f, 0.f, 0.f, 0.f}, s1 = {0.f, 0.f, 0.f, 0.f};
#pragma unroll
    for (int ks = 0; ks < KSPLIT; ++ks) {
      const float* p = aggP + ((size_t)ks * NN + m0 + r_) * 128 + c8;
      float4 a0 = *(const float4*)p, a1 = *(const float4*)(p + 4);
      s0.x += a0.x; s0.y += a0.y; s0.z += a0.z; s0.w += a0.w;
      s1.x += a1.x; s1.y += a1.y; s1.z += a1.z; s1.w += a1.w;
    }
    s0.x *= inv; s0.y *= inv; s0.z *= inv; s0.w *= inv;
    s1.x *= inv; s1.y *= inv; s1.z *= inv; s1.w *= inv;
    *(ushort4*)&aggL[r_ * LSTR + c8] = f2bf4(s0);
    *(ushort4*)&aggL[r_ * LSTR + c8 + 4] = f2bf4(s1);
    *(int4*)&nfL[r_ * LSTR + c8] = *(const int4*)&nfB[(size_t)(m0 + r_) * 128 + c8];
  }
  __syncthreads();

  const int lane = t & 63, wave = t >> 6;
  const int quad = lane >> 4, l16 = lane & 15;
  const int rt = wave >> 2;                       // 2 row-tiles of 16
  const int ct0 = (wave & 3) * 2, ct1 = ct0 + 1;  // 2 col-tiles per wave

  bf16x8 aA[4], aN[4];
  for (int kk = 0; kk < 4; ++kk) {
    aA[kk] = *(const bf16x8*)&aggL[(rt * 16 + l16) * LSTR + kk * 32 + quad * 8];
    aN[kk] = *(const bf16x8*)&nfL[(rt * 16 + l16) * LSTR + kk * 32 + quad * 8];
  }

  float gate[2][4];
  const int order[3] = {0, 2, 1};  // r -> n -> z
  for (int ci = 0; ci < 3; ++ci) {
    const int c = order[ci];
    f32x4 ai[2], ah[2];
    for (int j = 0; j < 2; ++j) {
      const int o = (j ? ct1 : ct0) * 16 + l16;
      const unsigned short* wb = wihB + c * 16384 + o * 128;
      f32x4 acc = {0.f, 0.f, 0.f, 0.f};
      for (int kk = 0; kk < 4; ++kk) {
        bf16x8 b = *(const bf16x8*)&wb[kk * 32 + quad * 8];
        acc = __builtin_amdgcn_mfma_f32_16x16x32_bf16(aA[kk], b, acc, 0, 0, 0);
      }
      ai[j] = acc;
    }
    for (int j = 0; j < 2; ++j) {
      const int o = (j ? ct1 : ct0) * 16 + l16;
      const unsigned short* wb = whhB + c * 16384 + o * 128;
      f32x4 acc = {0.f, 0.f, 0.f, 0.f};
      for (int kk = 0; kk < 4; ++kk) {
        bf16x8 b = *(const bf16x8*)&wb[kk * 32 + quad * 8];
        acc = __builtin_amdgcn_mfma_f32_16x16x32_bf16(aN[kk], b, acc, 0, 0, 0);
      }
      ah[j] = acc;
    }
    for (int j = 0; j < 2; ++j) {
      const int col = (j ? ct1 : ct0) * 16 + l16;
      const float bi = b_ih[c * 128 + col];
      const float bh = b_hh[c * 128 + col];
      for (int r = 0; r < 4; ++r) {
        const float gi = ai[j][r] + bi;
        const float gh = ah[j][r] + bh;
        if (c == 0) {
          gate[j][r] = sigmoidf_(gi + gh);                 // r
        } else if (c == 2) {
          gate[j][r] = tanhf_(gi + gate[j][r] * gh);       // n = tanh(i_n + r*h_n)
        } else {
          const float z = sigmoidf_(gi + gh);
          const int m = m0 + rt * 16 + quad * 4 + r;
          const float h = nf[m * 128 + col];
          out[m * 128 + col] = (1.0f - z) * gate[j][r] + z * h;
        }
      }
    }
  }
}

extern "C" void kernel_launch(void* const* d_in, const int* in_sizes, int n_in,
                              void* d_out, int out_size, void* d_ws, size_t ws_size,
                              hipStream_t stream) {
  const float* nf   = (const float*)d_in[0];
  const int*   adj  = (const int*)d_in[1];
  const float* wmsg = (const float*)d_in[2];
  const float* bmsg = (const float*)d_in[3];
  const float* wih  = (const float*)d_in[4];
  const float* whh  = (const float*)d_in[5];
  const float* bih  = (const float*)d_in[6];
  const float* bhh  = (const float*)d_in[7];
  float* out = (float*)d_out;

  // ws: msgT 2MB | nfB 2MB | aggP 32MB | degP 256KB | wihB 96KB | whhB 96KB
  unsigned short* msgT = (unsigned short*)d_ws;
  unsigned short* nfB  = msgT + (size_t)NN * DIM;
  float* aggP          = (float*)(nfB + (size_t)NN * DIM);
  int* degP            = (int*)(aggP + (size_t)KSPLIT * NN * DIM);
  unsigned short* wihB = (unsigned short*)(degP + KSPLIT * NN);
  unsigned short* whhB = wihB + 3 * DIM * DIM;

  k1_msg<<<NN / 32, 256, 0, stream>>>(nf, wmsg, bmsg, msgT, nfB, wih, whh, wihB, whhB);
  k2_agg<<<(NN / 32) * KSPLIT, 512, 0, stream>>>(adj, msgT, aggP, degP);
  k3_gru<<<NN / 32, 512, 0, stream>>>(nf, aggP, degP, wihB, whhB, bih, bhh, nfB, out);
}

// Round 10
// 402.775 us; speedup vs baseline: 1.1187x; 1.1187x over previous
//
#include <hip/hip_runtime.h>

// GNN layer: messages = relu(NF @ Wm^T + bm); agg = (adj @ messages)/deg; GRU(agg, NF)
// N=8192, D=128. adj read 268 MB = the only unavoidable HBM (43us @6.3TB/s).
// V9 = exact revert to the R1/V2 configuration -- the session best (401.8us).
// K2 ledger: V2~104 | V3 173 (grid-starved) | V4/V5 163 (spilled, VGPR=64) |
// V6 221 (serialized, VGPR=68) | V7~118 (KSPLIT=8) | V8b~152 (1-barrier BK=64 DMA).
// Every deviation from V2 regressed; the ~300us residual = fill(160) + input
// restore(~85) + K1/K3(~25) is harness-side. V2's recipe: small per-thread state
// (acc 8 VGPR + 6-int4 prefetch) + 512thr blocks + prefetch issued AFTER the
// staging barrier so it flies across the whole compute phase.

#define NN 8192
#define DIM 128
#define LSTR 136  // 128 + 8 bf16 pad: breaks bank conflicts, keeps 16B align

typedef __bf16 bf16x8 __attribute__((ext_vector_type(8)));
typedef float f32x4 __attribute__((ext_vector_type(4)));

__device__ __forceinline__ unsigned short f2bf(float f) {
  union { float f; unsigned u; } v; v.f = f;
  unsigned r = v.u + 0x7FFF + ((v.u >> 16) & 1);  // RNE
  return (unsigned short)(r >> 16);
}
__device__ __forceinline__ ushort4 f2bf4(float4 f) {
  ushort4 u; u.x = f2bf(f.x); u.y = f2bf(f.y); u.z = f2bf(f.z); u.w = f2bf(f.w);
  return u;
}
__device__ __forceinline__ float sigmoidf_(float x) {
  return 1.0f / (1.0f + __expf(-x));
}
__device__ __forceinline__ float tanhf_(float x) {
  float e = __expf(-2.0f * fabsf(x));
  float r = (1.0f - e) / (1.0f + e);
  return x < 0.0f ? -r : r;
}

// ---------------- K1: msgT[o][m] = relu(NF @ Wm^T + bm) (bf16, transposed).
// Side jobs: nfB = bf16(nf), wihB/whhB = bf16 GRU weights (converted once).
__global__ __launch_bounds__(256) void k1_msg(
    const float* __restrict__ nf, const float* __restrict__ w_msg,
    const float* __restrict__ b_msg, unsigned short* __restrict__ msgT,
    unsigned short* __restrict__ nfB, const float* __restrict__ w_ih,
    const float* __restrict__ w_hh, unsigned short* __restrict__ wihB,
    unsigned short* __restrict__ whhB) {
  __shared__ unsigned short wm[128 * LSTR];   // wm[o][k] bf16
  __shared__ unsigned short nfl[32 * LSTR];   // nf tile [m][k] bf16
  const int t = threadIdx.x;
  const int m0 = blockIdx.x * 32;

  const int gtid = blockIdx.x * 256 + t;
  if (gtid < 12288) {
    ((ushort4*)wihB)[gtid] = f2bf4(((const float4*)w_ih)[gtid]);
  } else if (gtid < 24576) {
    ((ushort4*)whhB)[gtid - 12288] = f2bf4(((const float4*)w_hh)[gtid - 12288]);
  }
  for (int i = t; i < 4096; i += 256) {
    float4 v = ((const float4*)w_msg)[i];
    const int row = i >> 5, col = (i & 31) * 4;
    *(ushort4*)&wm[row * LSTR + col] = f2bf4(v);
  }
  for (int i = t; i < 1024; i += 256) {
    float4 v = ((const float4*)(nf + m0 * 128))[i];
    ushort4 u = f2bf4(v);
    const int row = i >> 5, col = (i & 31) * 4;
    *(ushort4*)&nfl[row * LSTR + col] = u;
    *(ushort4*)&nfB[(m0 + row) * 128 + col] = u;
  }
  __syncthreads();

  const int lane = t & 63, wave = t >> 6;
  const int quad = lane >> 4, l16 = lane & 15;
  const int rt = wave >> 1, ch = wave & 1;
  f32x4 acc[4];
  for (int j = 0; j < 4; ++j) acc[j] = (f32x4){0.f, 0.f, 0.f, 0.f};
  for (int kk = 0; kk < 4; ++kk) {
    bf16x8 a = *(const bf16x8*)&nfl[(rt * 16 + l16) * LSTR + kk * 32 + quad * 8];
    for (int j = 0; j < 4; ++j) {
      const int ct = ch * 4 + j;
      bf16x8 b = *(const bf16x8*)&wm[(ct * 16 + l16) * LSTR + kk * 32 + quad * 8];
      acc[j] = __builtin_amdgcn_mfma_f32_16x16x32_bf16(a, b, acc[j], 0, 0, 0);
    }
  }
  const int mb = m0 + rt * 16 + quad * 4;
  for (int j = 0; j < 4; ++j) {
    const int o = (ch * 4 + j) * 16 + l16;
    const float bias = b_msg[o];
    ushort4 u;
    u.x = f2bf(fmaxf(acc[j][0] + bias, 0.0f));
    u.y = f2bf(fmaxf(acc[j][1] + bias, 0.0f));
    u.z = f2bf(fmaxf(acc[j][2] + bias, 0.0f));
    u.w = f2bf(fmaxf(acc[j][3] + bias, 0.0f));
    *(ushort4*)&msgT[o * NN + mb] = u;
  }
}

// ---------------- K2: aggP[ks][m][o] = sum_{k in half ks} adj[m][k]*msg[k][o] (f32),
// degP[ks][m] = row-degree partial. K-split=2 -> grid 512 = 2 blocks/CU.
// 512 thr (8 waves), M-tile 32, BK 128, register-prefetch single-buffer LDS,
// prefetch issued AFTER the staging barrier (flies across compute).
__global__ __launch_bounds__(512) void k2_agg(
    const int* __restrict__ adj, const unsigned short* __restrict__ msgT,
    float* __restrict__ aggP, int* __restrict__ degP) {
  __shared__ unsigned short adjL[32 * LSTR];   // A tile [m][k] bf16 (0/1)
  __shared__ unsigned short msgL[128 * LSTR];  // B tile [o][k] bf16
  __shared__ int degS[32];
  const int t = threadIdx.x;
  const int m0 = (blockIdx.x & 255) * 32;
  const int ks = blockIdx.x >> 8;
  const int kbase = ks * 4096;
  if (t < 32) degS[t] = 0;

  const int ar = t >> 5;         // 0..15
  const int as = t & 31;         // int4 segment within row
  const int mn = t >> 4;         // 0..31
  const int mko = (t & 15) * 8;

  const int* aB0 = adj + (size_t)(m0 + ar) * NN + kbase + as * 4;
  const int* aB1 = aB0 + (size_t)16 * NN;
  const unsigned short* mB0 = msgT + (size_t)(mn +  0) * NN + kbase + mko;
  const unsigned short* mB1 = msgT + (size_t)(mn + 32) * NN + kbase + mko;
  const unsigned short* mB2 = msgT + (size_t)(mn + 64) * NN + kbase + mko;
  const unsigned short* mB3 = msgT + (size_t)(mn + 96) * NN + kbase + mko;

  int deg0 = 0, deg1 = 0;
  int4 pa0 = *(const int4*)aB0;
  int4 pa1 = *(const int4*)aB1;
  int4 pm0 = *(const int4*)mB0;
  int4 pm1 = *(const int4*)mB1;
  int4 pm2 = *(const int4*)mB2;
  int4 pm3 = *(const int4*)mB3;

  const int lane = t & 63, wave = t >> 6;
  const int quad = lane >> 4, l16 = lane & 15;
  const int rt = wave >> 2;
  const int ct0 = (wave & 3) * 2, ct1 = ct0 + 1;
  f32x4 acc0 = {0.f, 0.f, 0.f, 0.f}, acc1 = {0.f, 0.f, 0.f, 0.f};

  const int aOff  = (rt * 16 + l16) * LSTR + quad * 8;
  const int bOff0 = (ct0 * 16 + l16) * LSTR + quad * 8;
  const int bOff1 = (ct1 * 16 + l16) * LSTR + quad * 8;

  for (int c = 0; c < 32; ++c) {
    ushort4 w0, w1;
    w0.x = pa0.x ? 0x3F80 : 0; w0.y = pa0.y ? 0x3F80 : 0;
    w0.z = pa0.z ? 0x3F80 : 0; w0.w = pa0.w ? 0x3F80 : 0;
    w1.x = pa1.x ? 0x3F80 : 0; w1.y = pa1.y ? 0x3F80 : 0;
    w1.z = pa1.z ? 0x3F80 : 0; w1.w = pa1.w ? 0x3F80 : 0;
    deg0 += pa0.x + pa0.y + pa0.z + pa0.w;
    deg1 += pa1.x + pa1.y + pa1.z + pa1.w;
    *(ushort4*)&adjL[ar * LSTR + as * 4] = w0;
    *(ushort4*)&adjL[(16 + ar) * LSTR + as * 4] = w1;
    *(int4*)&msgL[(mn +  0) * LSTR + mko] = pm0;
    *(int4*)&msgL[(mn + 32) * LSTR + mko] = pm1;
    *(int4*)&msgL[(mn + 64) * LSTR + mko] = pm2;
    *(int4*)&msgL[(mn + 96) * LSTR + mko] = pm3;
    __syncthreads();
    if (c < 31) {
      const int k0 = (c + 1) * 128;
      pa0 = *(const int4*)(aB0 + k0);
      pa1 = *(const int4*)(aB1 + k0);
      pm0 = *(const int4*)(mB0 + k0);
      pm1 = *(const int4*)(mB1 + k0);
      pm2 = *(const int4*)(mB2 + k0);
      pm3 = *(const int4*)(mB3 + k0);
    }
    for (int kk = 0; kk < 4; ++kk) {
      bf16x8 a  = *(const bf16x8*)&adjL[aOff  + kk * 32];
      bf16x8 b0 = *(const bf16x8*)&msgL[bOff0 + kk * 32];
      bf16x8 b1 = *(const bf16x8*)&msgL[bOff1 + kk * 32];
      acc0 = __builtin_amdgcn_mfma_f32_16x16x32_bf16(a, b0, acc0, 0, 0, 0);
      acc1 = __builtin_amdgcn_mfma_f32_16x16x32_bf16(a, b1, acc1, 0, 0, 0);
    }
    __syncthreads();
  }
  atomicAdd(&degS[ar], deg0);
  atomicAdd(&degS[16 + ar], deg1);
  __syncthreads();
  float* dst = aggP + (size_t)ks * NN * 128;
  for (int r = 0; r < 4; ++r) {
    const int rowL = rt * 16 + quad * 4 + r;
    const int m = m0 + rowL;
    dst[m * 128 + ct0 * 16 + l16] = acc0[r];
    dst[m * 128 + ct1 * 16 + l16] = acc1[r];
  }
  if (t < 32) degP[ks * NN + m0 + t] = degS[t];
}

// ---------------- K3: fused GRU. agg = (P0+P1)/deg combined f32 at staging;
// B-frags direct from bf16 weights (L2-resident), 1 barrier total.
__global__ __launch_bounds__(256) void k3_gru(
    const float* __restrict__ nf, const float* __restrict__ aggP,
    const int* __restrict__ degP, const unsigned short* __restrict__ wihB,
    const unsigned short* __restrict__ whhB, const float* __restrict__ b_ih,
    const float* __restrict__ b_hh, const unsigned short* __restrict__ nfB,
    float* __restrict__ out) {
  __shared__ unsigned short aggL[16 * LSTR];
  __shared__ unsigned short nfL[16 * LSTR];
  const int t = threadIdx.x;
  const int m0 = blockIdx.x * 16;
  {
    const int r_ = t >> 4, c8 = (t & 15) * 8;
    const float inv =
        1.0f / fmaxf((float)(degP[m0 + r_] + degP[NN + m0 + r_]), 1.0f);
    const float* p0 = aggP + (size_t)(m0 + r_) * 128 + c8;
    const float* p1 = p0 + (size_t)NN * 128;
    float4 a0 = *(const float4*)p0, a1 = *(const float4*)(p0 + 4);
    float4 b0 = *(const float4*)p1, b1 = *(const float4*)(p1 + 4);
    float4 s0, s1;
    s0.x = (a0.x + b0.x) * inv; s0.y = (a0.y + b0.y) * inv;
    s0.z = (a0.z + b0.z) * inv; s0.w = (a0.w + b0.w) * inv;
    s1.x = (a1.x + b1.x) * inv; s1.y = (a1.y + b1.y) * inv;
    s1.z = (a1.z + b1.z) * inv; s1.w = (a1.w + b1.w) * inv;
    *(ushort4*)&aggL[r_ * LSTR + c8] = f2bf4(s0);
    *(ushort4*)&aggL[r_ * LSTR + c8 + 4] = f2bf4(s1);
    *(int4*)&nfL[r_ * LSTR + c8] = *(const int4*)&nfB[(m0 + r_) * 128 + c8];
  }
  __syncthreads();

  const int lane = t & 63, wave = t >> 6;
  const int quad = lane >> 4, l16 = lane & 15;
  const int ct0 = wave * 2, ct1 = ct0 + 1;  // 4 waves x 2 col-tiles = 128 cols

  bf16x8 aA[4], aN[4];
  for (int kk = 0; kk < 4; ++kk) {
    aA[kk] = *(const bf16x8*)&aggL[l16 * LSTR + kk * 32 + quad * 8];
    aN[kk] = *(const bf16x8*)&nfL[l16 * LSTR + kk * 32 + quad * 8];
  }

  float gate[2][4];
  const int order[3] = {0, 2, 1};  // r -> n -> z
  for (int ci = 0; ci < 3; ++ci) {
    const int c = order[ci];
    f32x4 ai[2], ah[2];
    for (int j = 0; j < 2; ++j) {
      const int o = (j ? ct1 : ct0) * 16 + l16;
      const unsigned short* wb = wihB + c * 16384 + o * 128;
      f32x4 acc = {0.f, 0.f, 0.f, 0.f};
      for (int kk = 0; kk < 4; ++kk) {
        bf16x8 b = *(const bf16x8*)&wb[kk * 32 + quad * 8];
        acc = __builtin_amdgcn_mfma_f32_16x16x32_bf16(aA[kk], b, acc, 0, 0, 0);
      }
      ai[j] = acc;
    }
    for (int j = 0; j < 2; ++j) {
      const int o = (j ? ct1 : ct0) * 16 + l16;
      const unsigned short* wb = whhB + c * 16384 + o * 128;
      f32x4 acc = {0.f, 0.f, 0.f, 0.f};
      for (int kk = 0; kk < 4; ++kk) {
        bf16x8 b = *(const bf16x8*)&wb[kk * 32 + quad * 8];
        acc = __builtin_amdgcn_mfma_f32_16x16x32_bf16(aN[kk], b, acc, 0, 0, 0);
      }
      ah[j] = acc;
    }
    for (int j = 0; j < 2; ++j) {
      const int col = (j ? ct1 : ct0) * 16 + l16;
      const float bi = b_ih[c * 128 + col];
      const float bh = b_hh[c * 128 + col];
      for (int r = 0; r < 4; ++r) {
        const float gi = ai[j][r] + bi;
        const float gh = ah[j][r] + bh;
        if (c == 0) {
          gate[j][r] = sigmoidf_(gi + gh);                 // r
        } else if (c == 2) {
          gate[j][r] = tanhf_(gi + gate[j][r] * gh);       // n = tanh(i_n + r*h_n)
        } else {
          const float z = sigmoidf_(gi + gh);
          const int m = m0 + quad * 4 + r;
          const float h = nf[m * 128 + col];
          out[m * 128 + col] = (1.0f - z) * gate[j][r] + z * h;
        }
      }
    }
  }
}

extern "C" void kernel_launch(void* const* d_in, const int* in_sizes, int n_in,
                              void* d_out, int out_size, void* d_ws, size_t ws_size,
                              hipStream_t stream) {
  const float* nf   = (const float*)d_in[0];
  const int*   adj  = (const int*)d_in[1];
  const float* wmsg = (const float*)d_in[2];
  const float* bmsg = (const float*)d_in[3];
  const float* wih  = (const float*)d_in[4];
  const float* whh  = (const float*)d_in[5];
  const float* bih  = (const float*)d_in[6];
  const float* bhh  = (const float*)d_in[7];
  float* out = (float*)d_out;

  // ws layout (all 16B-aligned): msgT 2MB | nfB 2MB | aggP 8MB | degP 64KB | wihB | whhB
  unsigned short* msgT = (unsigned short*)d_ws;            // bf16 [128][8192]
  unsigned short* nfB  = msgT + (size_t)NN * DIM;          // bf16 [8192][128]
  float* aggP          = (float*)(nfB + (size_t)NN * DIM); // f32  [2][8192][128]
  int* degP            = (int*)(aggP + (size_t)2 * NN * DIM); // i32 [2][8192]
  unsigned short* wihB = (unsigned short*)(degP + 2 * NN); // bf16 [3][128][128]
  unsigned short* whhB = wihB + 3 * DIM * DIM;             // bf16 [3][128][128]

  k1_msg<<<NN / 32, 256, 0, stream>>>(nf, wmsg, bmsg, msgT, nfB, wih, whh, wihB, whhB);
  k2_agg<<<2 * (NN / 32), 512, 0, stream>>>(adj, msgT, aggP, degP);
  k3_gru<<<NN / 16, 256, 0, stream>>>(nf, aggP, degP, wihB, whhB, bih, bhh, nfB, out);
}